// Round 5
// baseline (309.551 us; speedup 1.0000x reference)
//
#include <hip/hip_runtime.h>
#include <hip/hip_cooperative_groups.h>

namespace cg = cooperative_groups;

#define NG 2
#define NV 320
#define GV 640      // NG*NV
#define DHALF 128   // CODE_DIM/NG
#define BSROWS 2048 // B*S
#define NROWS 4096  // BSROWS*NG
#define K_DIM 512
#define NBLK 512    // fused-kernel grid
#define NPART_FB 1024
#define LDAs 40     // f16 per LDS row (32 + 8 pad)

typedef _Float16 half8 __attribute__((ext_vector_type(8)));
typedef _Float16 half4 __attribute__((ext_vector_type(4)));
typedef float floatx4 __attribute__((ext_vector_type(4)));

#define MFMA16(a, b, c) __builtin_amdgcn_mfma_f32_16x16x32_f16(a, b, c, 0, 0, 0)

// ============================ FUSED COOPERATIVE KERNEL =====================================
__global__ __launch_bounds__(256, 2) void fused_kernel(
    const float* __restrict__ X, const float* __restrict__ Wg,
    const float* __restrict__ bias, const float* __restrict__ cvs,
    const float* __restrict__ gum, float* __restrict__ out,
    float* __restrict__ logits, float* __restrict__ part,
    float* __restrict__ hpart, _Float16* __restrict__ Wth,
    _Float16* __restrict__ Wtl) {
  cg::grid_group grid = cg::this_grid();
  __shared__ __align__(16) char smem[20480];
  const int tid = threadIdx.x;
  const int bid = blockIdx.x;
  const int lane = tid & 63;
  const int w = tid >> 6;

  // ---------- P0: W[512][640] f32 -> Wth/Wtl [640][512] f16 (x1024 split) ----------
  if (bid < 320) {
    float(*T)[33] = (float(*)[33])smem;
    const int n0 = (bid % 20) * 32, k0 = (bid / 20) * 32;
    const int r = tid >> 3, c4 = (tid & 7) << 2;
    float4 v = *(const float4*)(Wg + (k0 + r) * GV + n0 + c4);
    T[r][c4 + 0] = v.x; T[r][c4 + 1] = v.y; T[r][c4 + 2] = v.z; T[r][c4 + 3] = v.w;
    __syncthreads();
    const int nr = tid >> 3, k4 = (tid & 7) << 2;
    half4 hv, lv;
#pragma unroll
    for (int j = 0; j < 4; ++j) {
      float s = T[k4 + j][nr] * 1024.0f;
      _Float16 h = (_Float16)s;
      hv[j] = h;
      lv[j] = (_Float16)(s - (float)h);
    }
    *(half4*)(Wth + (n0 + nr) * K_DIM + k0 + k4) = hv;
    *(half4*)(Wtl + (n0 + nr) * K_DIM + k0 + k4) = lv;
  }
  grid.sync();

  // ---------- P1: GEMM logits = x@W + b (LDS-staged, f16x2-split MFMA) ----------
  if (bid < 320) {
    _Float16* Ah = (_Float16*)smem;
    _Float16* Al = Ah + 64 * LDAs;
    _Float16* Bh = Al + 64 * LDAs;
    _Float16* Bl = Bh + 64 * LDAs;
    const int bm = (bid / 10) * 64, bn = (bid % 10) * 64;
    const int wr = w >> 1, wc = w & 1;
    const int srow = tid >> 2;
    const int skc = (tid & 3) << 3;
    const float* Xg = X + (bm + srow) * K_DIM + skc;
    const _Float16* Bhg = Wth + (bn + srow) * K_DIM + skc;
    const _Float16* Blg = Wtl + (bn + srow) * K_DIM + skc;
    const int sA = srow * LDAs + skc;
    const int frow = lane & 15;
    const int fkg = (lane >> 4) << 3;
    const int a0o = (wr * 32 + frow) * LDAs + fkg;
    const int b0o = (wc * 32 + frow) * LDAs + fkg;

    floatx4 acc[2][2] = {};

    for (int k0 = 0; k0 < K_DIM; k0 += 32) {
      float4 xa = *(const float4*)(Xg + k0);
      float4 xb = *(const float4*)(Xg + k0 + 4);
      half8 bhv = *(const half8*)(Bhg + k0);
      half8 blv = *(const half8*)(Blg + k0);
      __syncthreads();
      float xv[8] = {xa.x, xa.y, xa.z, xa.w, xb.x, xb.y, xb.z, xb.w};
      half8 hv, lv;
#pragma unroll
      for (int j = 0; j < 8; ++j) {
        float s = xv[j] * 64.0f;
        _Float16 h = (_Float16)s;
        hv[j] = h;
        lv[j] = (_Float16)(s - (float)h);
      }
      *(half8*)&Ah[sA] = hv;
      *(half8*)&Al[sA] = lv;
      *(half8*)&Bh[sA] = bhv;
      *(half8*)&Bl[sA] = blv;
      __syncthreads();

      half8 ah0 = *(const half8*)&Ah[a0o];
      half8 ah1 = *(const half8*)&Ah[a0o + 16 * LDAs];
      half8 al0 = *(const half8*)&Al[a0o];
      half8 al1 = *(const half8*)&Al[a0o + 16 * LDAs];
      half8 bh0 = *(const half8*)&Bh[b0o];
      half8 bh1 = *(const half8*)&Bh[b0o + 16 * LDAs];
      half8 bl0 = *(const half8*)&Bl[b0o];
      half8 bl1 = *(const half8*)&Bl[b0o + 16 * LDAs];

      acc[0][0] = MFMA16(ah0, bh0, acc[0][0]);
      acc[0][1] = MFMA16(ah0, bh1, acc[0][1]);
      acc[1][0] = MFMA16(ah1, bh0, acc[1][0]);
      acc[1][1] = MFMA16(ah1, bh1, acc[1][1]);
      acc[0][0] = MFMA16(ah0, bl0, acc[0][0]);
      acc[0][1] = MFMA16(ah0, bl1, acc[0][1]);
      acc[1][0] = MFMA16(ah1, bl0, acc[1][0]);
      acc[1][1] = MFMA16(ah1, bl1, acc[1][1]);
      acc[0][0] = MFMA16(al0, bh0, acc[0][0]);
      acc[0][1] = MFMA16(al0, bh1, acc[0][1]);
      acc[1][0] = MFMA16(al1, bh0, acc[1][0]);
      acc[1][1] = MFMA16(al1, bh1, acc[1][1]);
    }

    const float inv = 1.0f / 65536.0f;
#pragma unroll
    for (int i = 0; i < 2; ++i)
#pragma unroll
      for (int j = 0; j < 2; ++j) {
        const int col = bn + wc * 32 + j * 16 + (lane & 15);
        const int r0 = bm + wr * 32 + i * 16 + ((lane >> 4) << 2);
        const float bb = bias[col];
#pragma unroll
        for (int q = 0; q < 4; ++q)
          logits[(r0 + q) * GV + col] = acc[i][j][q] * inv + bb;
      }
  }
  grid.sync();

  // ---------- P2: per-bs row phase (both groups), fused gather, block partials ----------
  {
    float(*accW)[2][NV] = (float(*)[2][NV])smem;
    const int bs = bid * 4 + w;  // 0..2047
#pragma unroll
    for (int g = 0; g < 2; ++g) {
      const float* lrow = logits + bs * GV + g * NV;
      const float* grow = gum + (2 * bs + g) * NV;
      float lv[5], av[5];
#pragma unroll
      for (int j = 0; j < 5; ++j) {
        lv[j] = lrow[lane + 64 * j];
        av[j] = lv[j] + grow[lane + 64 * j];
      }
      float m = lv[0];
#pragma unroll
      for (int j = 1; j < 5; ++j) m = fmaxf(m, lv[j]);
#pragma unroll
      for (int o = 32; o > 0; o >>= 1) m = fmaxf(m, __shfl_xor(m, o));
      float e[5];
      float s = 0.f;
#pragma unroll
      for (int j = 0; j < 5; ++j) {
        e[j] = expf(lv[j] - m);
        s += e[j];
      }
#pragma unroll
      for (int o = 32; o > 0; o >>= 1) s += __shfl_xor(s, o);
      const float inv = 1.f / s;
#pragma unroll
      for (int j = 0; j < 5; ++j) accW[w][g][lane + 64 * j] = e[j] * inv;

      float bv = av[0];
      int bi = lane;
#pragma unroll
      for (int j = 1; j < 5; ++j) {
        if (av[j] > bv) { bv = av[j]; bi = lane + 64 * j; }
      }
#pragma unroll
      for (int o = 32; o > 0; o >>= 1) {
        float ov = __shfl_xor(bv, o);
        int oi = __shfl_xor(bi, o);
        if (ov > bv || (ov == bv && oi < bi)) { bv = ov; bi = oi; }
      }
      const float2 cvv = *(const float2*)(cvs + (g * NV + bi) * DHALF + lane * 2);
      *(float2*)(out + bs * 256 + g * DHALF + lane * 2) = cvv;
    }
    __syncthreads();
    for (int i = tid; i < GV; i += 256) {
      const int g = (i < NV) ? 0 : 1;
      const int c = (i < NV) ? i : i - NV;
      part[bid * GV + i] =
          (accW[0][g][c] + accW[1][g][c]) + (accW[2][g][c] + accW[3][g][c]);
    }
  }
  grid.sync();

  // ---------- P3: column reduce over 512 partials + per-64-col entropy ----------
  if (bid < 10) {
    float(*red)[64] = (float(*)[64])smem;
    const int col = bid * 64 + lane;
    float s = 0.f;
    for (int b = w; b < NBLK; b += 4) s += part[b * GV + col];
    red[w][lane] = s;
    __syncthreads();
    if (w == 0) {
      const float cs = red[0][lane] + red[1][lane] + red[2][lane] + red[3][lane];
      const float mm = cs * (1.0f / BSROWS);
      float h = mm * logf(mm + 1e-7f);
#pragma unroll
      for (int o = 32; o > 0; o >>= 1) h += __shfl_xor(h, o);
      if (lane == 0) hpart[bid] = h;
    }
  }
  grid.sync();

  // ---------- P4: perplexity ----------
  if (bid == 0 && tid == 0) {
    float h0 = 0.f, h1 = 0.f;
#pragma unroll
    for (int i = 0; i < 5; ++i) h0 += hpart[i];
#pragma unroll
    for (int i = 5; i < 10; ++i) h1 += hpart[i];
    out[BSROWS * 256] = expf(-h0) + expf(-h1);
  }
}

// ============================ FALLBACK PATH (round-3 pipeline) =============================
__global__ __launch_bounds__(256) void prep_w_kernel(
    const float* __restrict__ W, _Float16* __restrict__ Wth, _Float16* __restrict__ Wtl,
    int* __restrict__ counter) {
  __shared__ float T[32][33];
  const int k0 = blockIdx.y * 32, n0 = blockIdx.x * 32;
  const int t = threadIdx.x;
  if (blockIdx.x == 0 && blockIdx.y == 0 && t == 0) *counter = 0;
  const int r = t >> 3, c4 = (t & 7) << 2;
  float4 v = *(const float4*)(W + (k0 + r) * GV + n0 + c4);
  T[r][c4 + 0] = v.x; T[r][c4 + 1] = v.y; T[r][c4 + 2] = v.z; T[r][c4 + 3] = v.w;
  __syncthreads();
  const int nr = t >> 3, k4 = (t & 7) << 2;
  half4 hv, lv;
#pragma unroll
  for (int j = 0; j < 4; ++j) {
    float s = T[k4 + j][nr] * 1024.0f;
    _Float16 h = (_Float16)s;
    hv[j] = h;
    lv[j] = (_Float16)(s - (float)h);
  }
  *(half4*)(Wth + (n0 + nr) * K_DIM + k0 + k4) = hv;
  *(half4*)(Wtl + (n0 + nr) * K_DIM + k0 + k4) = lv;
}

__global__ __launch_bounds__(256) void gemm_mfma_kernel(
    const float* __restrict__ X, const _Float16* __restrict__ Wth,
    const _Float16* __restrict__ Wtl, const float* __restrict__ bias,
    float* __restrict__ C) {
  __shared__ _Float16 Ah[64 * LDAs], Al[64 * LDAs], Bh[64 * LDAs], Bl[64 * LDAs];
  const int tid = threadIdx.x;
  const int bm = blockIdx.y * 64, bn = blockIdx.x * 64;
  const int w = tid >> 6, lane = tid & 63;
  const int wr = w >> 1, wc = w & 1;
  const int srow = tid >> 2;
  const int skc = (tid & 3) << 3;
  const float* Xg = X + (bm + srow) * K_DIM + skc;
  const _Float16* Bhg = Wth + (bn + srow) * K_DIM + skc;
  const _Float16* Blg = Wtl + (bn + srow) * K_DIM + skc;
  const int sA = srow * LDAs + skc;
  const int frow = lane & 15;
  const int fkg = (lane >> 4) << 3;
  const int a0o = (wr * 32 + frow) * LDAs + fkg;
  const int b0o = (wc * 32 + frow) * LDAs + fkg;
  floatx4 acc[2][2] = {};
  for (int k0 = 0; k0 < K_DIM; k0 += 32) {
    float4 xa = *(const float4*)(Xg + k0);
    float4 xb = *(const float4*)(Xg + k0 + 4);
    half8 bhv = *(const half8*)(Bhg + k0);
    half8 blv = *(const half8*)(Blg + k0);
    __syncthreads();
    float xv[8] = {xa.x, xa.y, xa.z, xa.w, xb.x, xb.y, xb.z, xb.w};
    half8 hv, lv;
#pragma unroll
    for (int j = 0; j < 8; ++j) {
      float s = xv[j] * 64.0f;
      _Float16 h = (_Float16)s;
      hv[j] = h;
      lv[j] = (_Float16)(s - (float)h);
    }
    *(half8*)&Ah[sA] = hv;
    *(half8*)&Al[sA] = lv;
    *(half8*)&Bh[sA] = bhv;
    *(half8*)&Bl[sA] = blv;
    __syncthreads();
    half8 ah0 = *(const half8*)&Ah[a0o];
    half8 ah1 = *(const half8*)&Ah[a0o + 16 * LDAs];
    half8 al0 = *(const half8*)&Al[a0o];
    half8 al1 = *(const half8*)&Al[a0o + 16 * LDAs];
    half8 bh0 = *(const half8*)&Bh[b0o];
    half8 bh1 = *(const half8*)&Bh[b0o + 16 * LDAs];
    half8 bl0 = *(const half8*)&Bl[b0o];
    half8 bl1 = *(const half8*)&Bl[b0o + 16 * LDAs];
    acc[0][0] = MFMA16(ah0, bh0, acc[0][0]);
    acc[0][1] = MFMA16(ah0, bh1, acc[0][1]);
    acc[1][0] = MFMA16(ah1, bh0, acc[1][0]);
    acc[1][1] = MFMA16(ah1, bh1, acc[1][1]);
    acc[0][0] = MFMA16(ah0, bl0, acc[0][0]);
    acc[0][1] = MFMA16(ah0, bl1, acc[0][1]);
    acc[1][0] = MFMA16(ah1, bl0, acc[1][0]);
    acc[1][1] = MFMA16(ah1, bl1, acc[1][1]);
    acc[0][0] = MFMA16(al0, bh0, acc[0][0]);
    acc[0][1] = MFMA16(al0, bh1, acc[0][1]);
    acc[1][0] = MFMA16(al1, bh0, acc[1][0]);
    acc[1][1] = MFMA16(al1, bh1, acc[1][1]);
  }
  const float inv = 1.0f / 65536.0f;
#pragma unroll
  for (int i = 0; i < 2; ++i)
#pragma unroll
    for (int j = 0; j < 2; ++j) {
      const int col = bn + wc * 32 + j * 16 + (lane & 15);
      const int r0 = bm + wr * 32 + i * 16 + ((lane >> 4) << 2);
      const float bb = bias[col];
#pragma unroll
      for (int q = 0; q < 4; ++q)
        C[(r0 + q) * GV + col] = acc[i][j][q] * inv + bb;
    }
}

__global__ __launch_bounds__(256) void row_kernel(
    const float* __restrict__ logits, const float* __restrict__ gumbels,
    const float* __restrict__ cvs, float* __restrict__ out,
    float* __restrict__ part) {
  __shared__ float accW[4][NV];
  const int tid = threadIdx.x;
  const int lane = tid & 63;
  const int w = tid >> 6;
  const int r = blockIdx.x * 4 + w;
  const int bs = r >> 1, g = r & 1;
  const float* lrow = logits + bs * GV + g * NV;
  const float* grow = gumbels + r * NV;
  float lv[5], av[5];
#pragma unroll
  for (int j = 0; j < 5; ++j) {
    lv[j] = lrow[lane + 64 * j];
    av[j] = lv[j] + grow[lane + 64 * j];
  }
  float m = lv[0];
#pragma unroll
  for (int j = 1; j < 5; ++j) m = fmaxf(m, lv[j]);
#pragma unroll
  for (int o = 32; o > 0; o >>= 1) m = fmaxf(m, __shfl_xor(m, o));
  float e[5];
  float s = 0.f;
#pragma unroll
  for (int j = 0; j < 5; ++j) {
    e[j] = expf(lv[j] - m);
    s += e[j];
  }
#pragma unroll
  for (int o = 32; o > 0; o >>= 1) s += __shfl_xor(s, o);
  const float inv = 1.f / s;
#pragma unroll
  for (int j = 0; j < 5; ++j) accW[w][lane + 64 * j] = e[j] * inv;
  float bv = av[0];
  int bi = lane;
#pragma unroll
  for (int j = 1; j < 5; ++j) {
    if (av[j] > bv) { bv = av[j]; bi = lane + 64 * j; }
  }
#pragma unroll
  for (int o = 32; o > 0; o >>= 1) {
    float ov = __shfl_xor(bv, o);
    int oi = __shfl_xor(bi, o);
    if (ov > bv || (ov == bv && oi < bi)) { bv = ov; bi = oi; }
  }
  const float2 cv = *(const float2*)(cvs + (g * NV + bi) * DHALF + lane * 2);
  *(float2*)(out + bs * 256 + g * DHALF + lane * 2) = cv;
  __syncthreads();
  for (int i = tid; i < GV; i += 256) {
    float v = (i < NV) ? (accW[0][i] + accW[2][i]) : (accW[1][i - NV] + accW[3][i - NV]);
    part[blockIdx.x * GV + i] = v;
  }
}

__global__ __launch_bounds__(256) void reduce_perp_kernel(
    const float* __restrict__ part, float* __restrict__ hpart,
    int* __restrict__ counter, float* __restrict__ perpOut) {
  const int t = threadIdx.x, lane = t & 63, w = t >> 6;
  const int col = blockIdx.x * 64 + lane;
  float s = 0.f;
  for (int b = w; b < NPART_FB; b += 4) s += part[b * GV + col];
  __shared__ float red[4][64];
  red[w][lane] = s;
  __syncthreads();
  if (w == 0) {
    const float cs = red[0][lane] + red[1][lane] + red[2][lane] + red[3][lane];
    const float mm = cs * (1.0f / BSROWS);
    float h = mm * logf(mm + 1e-7f);
#pragma unroll
    for (int o = 32; o > 0; o >>= 1) h += __shfl_xor(h, o);
    if (lane == 0) {
      hpart[blockIdx.x] = h;
      __threadfence();
      const int old = atomicAdd(counter, 1);
      if (old == 9) {
        __threadfence();
        float h0 = 0.f, h1 = 0.f;
#pragma unroll
        for (int i = 0; i < 5; ++i) h0 += hpart[i];
#pragma unroll
        for (int i = 5; i < 10; ++i) h1 += hpart[i];
        perpOut[0] = expf(-h0) + expf(-h1);
      }
    }
  }
}

// ============================ LAUNCH ========================================================
extern "C" void kernel_launch(void* const* d_in, const int* in_sizes, int n_in,
                              void* d_out, int out_size, void* d_ws, size_t ws_size,
                              hipStream_t stream) {
  const float* x = (const float*)d_in[0];
  const float* W = (const float*)d_in[1];
  const float* b = (const float*)d_in[2];
  const float* cvs = (const float*)d_in[3];
  const float* gum = (const float*)d_in[4];
  float* out = (float*)d_out;

  float* logits = (float*)d_ws;                      // 2048*640 f32
  float* part = logits + BSROWS * GV;                // 1024*640 f32 (covers both paths)
  float* hpart = part + NPART_FB * GV;               // 16 f32
  int* counter = (int*)(hpart + 16);                 // 1 i32 (+pad)
  _Float16* Wth = (_Float16*)(counter + 4);          // 640*512 f16
  _Float16* Wtl = Wth + GV * K_DIM;                  // 640*512 f16

  void* args[] = {(void*)&x,      (void*)&W,    (void*)&b,     (void*)&cvs,
                  (void*)&gum,    (void*)&out,  (void*)&logits, (void*)&part,
                  (void*)&hpart,  (void*)&Wth,  (void*)&Wtl};
  hipError_t err = hipLaunchCooperativeKernel((const void*)fused_kernel, dim3(NBLK),
                                              dim3(256), args, 0, stream);
  if (err != hipSuccess) {
    // fallback: discrete round-3 pipeline (identical math)
    dim3 pgrid(GV / 32, K_DIM / 32);
    prep_w_kernel<<<pgrid, 256, 0, stream>>>(W, Wth, Wtl, counter);
    dim3 ggrid(GV / 64, BSROWS / 64);
    gemm_mfma_kernel<<<ggrid, 256, 0, stream>>>(x, Wth, Wtl, b, logits);
    row_kernel<<<NROWS / 4, 256, 0, stream>>>(logits, gum, cvs, out, part);
    reduce_perp_kernel<<<GV / 64, 256, 0, stream>>>(part, hpart, counter, out + BSROWS * 256);
  }
}

// Round 6
// 54.132 us; speedup vs baseline: 5.7184x; 5.7184x over previous
//
#include <hip/hip_runtime.h>

#define NG 2
#define NV 320
#define GV 640      // NG*NV
#define DHALF 128   // CODE_DIM/NG
#define BSROWS 2048 // B*S
#define NROWS 4096  // BSROWS*NG
#define K_DIM 512
#define NPART 1024  // row-kernel blocks (partials)
#define LDAs 40     // f16 per LDS row (32 + 8 pad); 80 B, 16B-aligned
#define TILE (64 * LDAs)

typedef _Float16 half8 __attribute__((ext_vector_type(8)));
typedef _Float16 half4 __attribute__((ext_vector_type(4)));
typedef float floatx4 __attribute__((ext_vector_type(4)));

#define MFMA16(a, b, c) __builtin_amdgcn_mfma_f32_16x16x32_f16(a, b, c, 0, 0, 0)

// ---------------- Prep: W[512][640] f32 -> Wt_h/Wt_l [640][512] f16 (scale 1024); zero ctr --
__global__ __launch_bounds__(256) void prep_w_kernel(
    const float* __restrict__ W, _Float16* __restrict__ Wth, _Float16* __restrict__ Wtl,
    int* __restrict__ counter) {
  __shared__ float T[32][33];
  const int k0 = blockIdx.y * 32, n0 = blockIdx.x * 32;
  const int t = threadIdx.x;
  if (blockIdx.x == 0 && blockIdx.y == 0 && t == 0) *counter = 0;
  const int r = t >> 3, c4 = (t & 7) << 2;
  float4 v = *(const float4*)(W + (k0 + r) * GV + n0 + c4);
  T[r][c4 + 0] = v.x; T[r][c4 + 1] = v.y; T[r][c4 + 2] = v.z; T[r][c4 + 3] = v.w;
  __syncthreads();
  const int nr = t >> 3, k4 = (t & 7) << 2;
  half4 hv, lv;
#pragma unroll
  for (int j = 0; j < 4; ++j) {
    float s = T[k4 + j][nr] * 1024.0f;
    _Float16 h = (_Float16)s;
    hv[j] = h;
    lv[j] = (_Float16)(s - (float)h);
  }
  *(half4*)(Wth + (n0 + nr) * K_DIM + k0 + k4) = hv;
  *(half4*)(Wtl + (n0 + nr) * K_DIM + k0 + k4) = lv;
}

// ---------------- GEMM: logits = x @ W + b; f16x2-split MFMA; double-buffered LDS ----------
__global__ __launch_bounds__(256) void gemm_mfma_kernel(
    const float* __restrict__ X, const _Float16* __restrict__ Wth,
    const _Float16* __restrict__ Wtl, const float* __restrict__ bias,
    float* __restrict__ C) {
  __shared__ _Float16 Ah[2][TILE], Al[2][TILE], Bh[2][TILE], Bl[2][TILE];
  const int tid = threadIdx.x;
  const int bm = blockIdx.y * 64, bn = blockIdx.x * 64;
  const int w = tid >> 6, lane = tid & 63;
  const int wr = w >> 1, wc = w & 1;

  const int srow = tid >> 2;
  const int skc = (tid & 3) << 3;
  const float* Xg = X + (bm + srow) * K_DIM + skc;
  const _Float16* Bhg = Wth + (bn + srow) * K_DIM + skc;
  const _Float16* Blg = Wtl + (bn + srow) * K_DIM + skc;
  const int sA = srow * LDAs + skc;

  const int frow = lane & 15;
  const int fkg = (lane >> 4) << 3;
  const int a0o = (wr * 32 + frow) * LDAs + fkg;
  const int b0o = (wc * 32 + frow) * LDAs + fkg;

  floatx4 acc[2][2] = {};

  // prologue: stage tile 0 into buffer 0
  {
    float4 xa = *(const float4*)(Xg);
    float4 xb = *(const float4*)(Xg + 4);
    half8 bhv = *(const half8*)(Bhg);
    half8 blv = *(const half8*)(Blg);
    float xv[8] = {xa.x, xa.y, xa.z, xa.w, xb.x, xb.y, xb.z, xb.w};
    half8 hv, lv;
#pragma unroll
    for (int j = 0; j < 8; ++j) {
      float s = xv[j] * 64.0f;
      _Float16 h = (_Float16)s;
      hv[j] = h;
      lv[j] = (_Float16)(s - (float)h);
    }
    *(half8*)&Ah[0][sA] = hv;
    *(half8*)&Al[0][sA] = lv;
    *(half8*)&Bh[0][sA] = bhv;
    *(half8*)&Bl[0][sA] = blv;
  }
  __syncthreads();

#pragma unroll 2
  for (int k0 = 0; k0 < K_DIM; k0 += 32) {
    const int cur = (k0 >> 5) & 1;
    const int nxt = cur ^ 1;
    const bool more = (k0 + 32) < K_DIM;

    // issue next tile's global loads early (hidden under MFMAs below)
    float4 xa, xb;
    half8 bhv, blv;
    if (more) {
      xa = *(const float4*)(Xg + k0 + 32);
      xb = *(const float4*)(Xg + k0 + 36);
      bhv = *(const half8*)(Bhg + k0 + 32);
      blv = *(const half8*)(Blg + k0 + 32);
    }

    // compute current tile
    half8 ah0 = *(const half8*)&Ah[cur][a0o];
    half8 ah1 = *(const half8*)&Ah[cur][a0o + 16 * LDAs];
    half8 al0 = *(const half8*)&Al[cur][a0o];
    half8 al1 = *(const half8*)&Al[cur][a0o + 16 * LDAs];
    half8 bh0 = *(const half8*)&Bh[cur][b0o];
    half8 bh1 = *(const half8*)&Bh[cur][b0o + 16 * LDAs];
    half8 bl0 = *(const half8*)&Bl[cur][b0o];
    half8 bl1 = *(const half8*)&Bl[cur][b0o + 16 * LDAs];

    acc[0][0] = MFMA16(ah0, bh0, acc[0][0]);
    acc[0][1] = MFMA16(ah0, bh1, acc[0][1]);
    acc[1][0] = MFMA16(ah1, bh0, acc[1][0]);
    acc[1][1] = MFMA16(ah1, bh1, acc[1][1]);
    acc[0][0] = MFMA16(ah0, bl0, acc[0][0]);
    acc[0][1] = MFMA16(ah0, bl1, acc[0][1]);
    acc[1][0] = MFMA16(ah1, bl0, acc[1][0]);
    acc[1][1] = MFMA16(ah1, bl1, acc[1][1]);
    acc[0][0] = MFMA16(al0, bh0, acc[0][0]);
    acc[0][1] = MFMA16(al0, bh1, acc[0][1]);
    acc[1][0] = MFMA16(al1, bh0, acc[1][0]);
    acc[1][1] = MFMA16(al1, bh1, acc[1][1]);

    // stage next tile into the other buffer
    if (more) {
      float xv[8] = {xa.x, xa.y, xa.z, xa.w, xb.x, xb.y, xb.z, xb.w};
      half8 hv, lv;
#pragma unroll
      for (int j = 0; j < 8; ++j) {
        float s = xv[j] * 64.0f;
        _Float16 h = (_Float16)s;
        hv[j] = h;
        lv[j] = (_Float16)(s - (float)h);
      }
      *(half8*)&Ah[nxt][sA] = hv;
      *(half8*)&Al[nxt][sA] = lv;
      *(half8*)&Bh[nxt][sA] = bhv;
      *(half8*)&Bl[nxt][sA] = blv;
    }
    __syncthreads();
  }

  // C/D layout: col = lane&15, row = (lane>>4)*4 + reg
  const float inv = 1.0f / 65536.0f;
#pragma unroll
  for (int i = 0; i < 2; ++i)
#pragma unroll
    for (int j = 0; j < 2; ++j) {
      const int col = bn + wc * 32 + j * 16 + (lane & 15);
      const int r0 = bm + wr * 32 + i * 16 + ((lane >> 4) << 2);
      const float bb = bias[col];
#pragma unroll
      for (int q = 0; q < 4; ++q)
        C[(r0 + q) * GV + col] = acc[i][j][q] * inv + bb;
    }
}

// ---------------- Row kernel: 1 row/wave; fused gather; per-block partials (round-3) -------
__global__ __launch_bounds__(256) void row_kernel(
    const float* __restrict__ logits, const float* __restrict__ gumbels,
    const float* __restrict__ cvs, float* __restrict__ out,
    float* __restrict__ part) {
  __shared__ float accW[4][NV];
  const int tid = threadIdx.x;
  const int lane = tid & 63;
  const int w = tid >> 6;
  const int r = blockIdx.x * 4 + w;  // row in [0,4096)
  const int bs = r >> 1, g = r & 1;
  const float* lrow = logits + bs * GV + g * NV;
  const float* grow = gumbels + r * NV;

  float lv[5], av[5];
#pragma unroll
  for (int j = 0; j < 5; ++j) {
    lv[j] = lrow[lane + 64 * j];
    av[j] = lv[j] + grow[lane + 64 * j];
  }
  float m = lv[0];
#pragma unroll
  for (int j = 1; j < 5; ++j) m = fmaxf(m, lv[j]);
#pragma unroll
  for (int o = 32; o > 0; o >>= 1) m = fmaxf(m, __shfl_xor(m, o));
  float e[5];
  float s = 0.f;
#pragma unroll
  for (int j = 0; j < 5; ++j) {
    e[j] = expf(lv[j] - m);
    s += e[j];
  }
#pragma unroll
  for (int o = 32; o > 0; o >>= 1) s += __shfl_xor(s, o);
  const float inv = 1.f / s;
#pragma unroll
  for (int j = 0; j < 5; ++j) accW[w][lane + 64 * j] = e[j] * inv;

  float bv = av[0];
  int bi = lane;
#pragma unroll
  for (int j = 1; j < 5; ++j) {
    if (av[j] > bv) { bv = av[j]; bi = lane + 64 * j; }
  }
#pragma unroll
  for (int o = 32; o > 0; o >>= 1) {
    float ov = __shfl_xor(bv, o);
    int oi = __shfl_xor(bi, o);
    if (ov > bv || (ov == bv && oi < bi)) { bv = ov; bi = oi; }
  }

  const float2 cv = *(const float2*)(cvs + (g * NV + bi) * DHALF + lane * 2);
  *(float2*)(out + bs * 256 + g * DHALF + lane * 2) = cv;

  __syncthreads();
  for (int i = tid; i < GV; i += 256) {
    float v = (i < NV) ? (accW[0][i] + accW[2][i]) : (accW[1][i - NV] + accW[3][i - NV]);
    part[blockIdx.x * GV + i] = v;
  }
}

// ---------------- Reduce partials + perplexity (last-block-done, validated round 4) --------
__global__ __launch_bounds__(256) void reduce_perp_kernel(
    const float* __restrict__ part, float* __restrict__ hpart,
    int* __restrict__ counter, float* __restrict__ perpOut) {
  const int t = threadIdx.x, lane = t & 63, w = t >> 6;
  const int col = blockIdx.x * 64 + lane;  // blocks 0..9; 0..4 group0, 5..9 group1
  float s0 = 0.f, s1 = 0.f, s2 = 0.f, s3 = 0.f;
  for (int b = w; b < NPART; b += 16) {
    s0 += part[(b + 0) * GV + col];
    s1 += part[(b + 4) * GV + col];
    s2 += part[(b + 8) * GV + col];
    s3 += part[(b + 12) * GV + col];
  }
  __shared__ float red[4][64];
  red[w][lane] = (s0 + s1) + (s2 + s3);
  __syncthreads();
  if (w == 0) {
    const float cs = red[0][lane] + red[1][lane] + red[2][lane] + red[3][lane];
    const float mm = cs * (1.0f / BSROWS);
    float h = mm * logf(mm + 1e-7f);
#pragma unroll
    for (int o = 32; o > 0; o >>= 1) h += __shfl_xor(h, o);
    if (lane == 0) {
      hpart[blockIdx.x] = h;
      __threadfence();
      const int old = atomicAdd(counter, 1);
      if (old == 9) {
        __threadfence();
        float h0 = 0.f, h1 = 0.f;
#pragma unroll
        for (int i = 0; i < 5; ++i) h0 += hpart[i];
#pragma unroll
        for (int i = 5; i < 10; ++i) h1 += hpart[i];
        perpOut[0] = expf(-h0) + expf(-h1);
      }
    }
  }
}

extern "C" void kernel_launch(void* const* d_in, const int* in_sizes, int n_in,
                              void* d_out, int out_size, void* d_ws, size_t ws_size,
                              hipStream_t stream) {
  const float* x = (const float*)d_in[0];
  const float* W = (const float*)d_in[1];
  const float* b = (const float*)d_in[2];
  const float* cvs = (const float*)d_in[3];
  const float* gum = (const float*)d_in[4];
  float* out = (float*)d_out;

  float* logits = (float*)d_ws;                     // 2048*640 f32
  float* part = logits + BSROWS * GV;               // 1024*640 f32
  float* hpart = part + NPART * GV;                 // 16 f32
  int* counter = (int*)(hpart + 16);                // 1 i32 (+pad)
  _Float16* Wth = (_Float16*)(counter + 4);         // 640*512 f16
  _Float16* Wtl = Wth + GV * K_DIM;                 // 640*512 f16

  dim3 pgrid(GV / 32, K_DIM / 32);  // (20, 16)
  prep_w_kernel<<<pgrid, 256, 0, stream>>>(W, Wth, Wtl, counter);
  dim3 ggrid(GV / 64, BSROWS / 64);  // (10, 32)
  gemm_mfma_kernel<<<ggrid, 256, 0, stream>>>(x, Wth, Wtl, b, logits);
  row_kernel<<<NROWS / 4, 256, 0, stream>>>(logits, gum, cvs, out, part);
  reduce_perp_kernel<<<GV / 64, 256, 0, stream>>>(part, hpart, counter, out + BSROWS * 256);
}